// Round 11
// baseline (261.002 us; speedup 1.0000x reference)
//
#include <hip/hip_runtime.h>
#include <stdint.h>

#define C_    19
#define NB    15
#define CB    (C_ * NB)          // 285 cells
#define HW    (512 * 1024)
#define NPIX  (4 * HW)           // 2097152
#define TPB   256                // 4 waves
#define WTILE 64                 // pixels per wave-tile (1 px/lane)
#define ROWS  20                 // 19 logit rows + 1 label row
#define NT    8                  // tiles per wave
#define GBLK  (NPIX / (WTILE * NT * 4))   // 1024 blocks = 4/CU exactly
#define KCOP  8                  // global histogram copies

// Wave-private DMA pipeline, v2: LDS = exactly 40960 B -> 4 blocks/CU
// (16 waves/CU, 4/SIMD). Cumulative register rows D0/D1/D2 (t<=1/2/3);
// bins telescoped at flush. Rare bin>=3 (~0.5/px) -> global atomics
// (fire-and-forget). No LDS hist, no barriers in main loop.
__global__ __launch_bounds__(TPB, 4)
void ece_hist(const float* __restrict__ logits,
              const int*   __restrict__ labels,
              float*       __restrict__ ws) {
    __shared__ uint32_t tile[4][2][ROWS][WTILE];  // 40960 B exactly

    const int tid  = threadIdx.x;
    const int wave = tid >> 6;
    const int lane = tid & 63;

    const int wgid = blockIdx.x * 4 + wave;       // global wave id
    const int px0  = wgid * (NT * WTILE);         // 512-px chunk, never straddles image
    const int b    = px0 >> 19;                   // HW = 2^19
    const int hw0  = px0 & (HW - 1);
    const float* lbase = logits + ((size_t)b * C_) * HW + hw0;

    float* wsb = ws + (size_t)(blockIdx.x & (KCOP - 1)) * CB;

    // Stage this wave's tile t into its buffer bb: 19 logit rows + label row.
    auto STAGE = [&](int t, int bb) {
#pragma unroll
        for (int r = 0; r < ROWS; ++r) {
            const uint32_t* src = (r < C_)
                ? (const uint32_t*)(lbase + (size_t)r * HW + t * WTILE) + lane
                : (const uint32_t*)(labels + px0 + t * WTILE) + lane;
            __builtin_amdgcn_global_load_lds(
                (const __attribute__((address_space(1))) void*)src,
                (__attribute__((address_space(3))) void*)&tile[wave][bb][r][0],
                4, 0, 0);                         // lane i -> base + 4i
        }
    };

    float D0[C_], D1[C_], D2[C_];                 // cumulative sums: t<=1, t<=2, t<=3
#pragma unroll
    for (int c = 0; c < C_; ++c) { D0[c] = 0.f; D1[c] = 0.f; D2[c] = 0.f; }

    STAGE(0, 0);
    for (int t = 0; t < NT; ++t) {
        const int cur = t & 1;
        if (t + 1 < NT) {
            STAGE(t + 1, cur ^ 1);
            // leaves exactly t+1's 20 stage loads in flight; drains prev-iter
            // rare atomics (issued ~1 iter ago, already acked) + tile t's rows
            asm volatile("s_waitcnt vmcnt(20)" ::: "memory");
        } else {
            asm volatile("s_waitcnt vmcnt(0)" ::: "memory");
        }
        __builtin_amdgcn_sched_barrier(0);        // keep ds_reads below the wait

        float x[C_];
#pragma unroll
        for (int c = 0; c < C_; ++c) x[c] = __uint_as_float(tile[wave][cur][c][lane]);
        const int l = (int)tile[wave][cur][C_][lane];

#pragma unroll
        for (int c = 0; c < C_; ++c) x[c] = __expf(x[c]);

        // pairwise-tree sum: a[0]=x0..7, a[4]=x8..15, a[8]=x16..18
        float a[10];
#pragma unroll
        for (int j = 0; j < 9; ++j) a[j] = x[2 * j] + x[2 * j + 1];
        a[9] = x[18];
        a[0] += a[1]; a[2] += a[3]; a[4] += a[5]; a[6] += a[7]; a[8] += a[9];
        a[0] += a[2]; a[4] += a[6];
        const float inv = 1.f / (a[0] + a[4] + a[8]);

#pragma unroll
        for (int c = 0; c < C_; ++c) {
            const float conf = x[c] * inv;
            const float tt   = conf * 15.f;      // ref bin = ceil(tt)-1 clamped
            const float val  = conf - ((c == l) ? 1.f : 0.f);
            D0[c] += (tt <= 1.f) ? val : 0.f;    // bin 0
            D1[c] += (tt <= 2.f) ? val : 0.f;    // bins <=1
            D2[c] += (tt <= 3.f) ? val : 0.f;    // bins <=2
            if (tt > 3.f) {                      // ~0.5/px: straight to global
                int bin = (int)ceilf(tt) - 1;
                bin = bin > NB - 1 ? NB - 1 : bin;
                atomicAdd(&wsb[c * NB + bin], val);
            }
        }
    }

    // Flush: 4-step xor-shuffle (16-lane groups) -> leaders fire global atomics.
    // Telescoping recovers exclusive bins: b0=D0, b1=D1-D0, b2=D2-D1.
#pragma unroll
    for (int c = 0; c < C_; ++c) {
        float r0 = D0[c], r1 = D1[c], r2 = D2[c];
        r0 += __shfl_xor(r0, 1); r1 += __shfl_xor(r1, 1); r2 += __shfl_xor(r2, 1);
        r0 += __shfl_xor(r0, 2); r1 += __shfl_xor(r1, 2); r2 += __shfl_xor(r2, 2);
        r0 += __shfl_xor(r0, 4); r1 += __shfl_xor(r1, 4); r2 += __shfl_xor(r2, 4);
        r0 += __shfl_xor(r0, 8); r1 += __shfl_xor(r1, 8); r2 += __shfl_xor(r2, 8);
        if ((tid & 15) == 0) {
            atomicAdd(&wsb[c * NB + 0], r0);
            atomicAdd(&wsb[c * NB + 1], r1 - r0);
            atomicAdd(&wsb[c * NB + 2], r2 - r1);
        }
    }
}

// Fold KCOP copies: sce = sum_cells |cell| / (N * C)
__global__ void ece_final(const float* __restrict__ ws, float* __restrict__ out) {
    const int t = threadIdx.x;  // 320 threads = 5 waves
    float val = 0.f;
    if (t < CB) {
        float s = 0.f;
#pragma unroll
        for (int k = 0; k < KCOP; ++k) s += ws[k * CB + t];
        val = fabsf(s);
    }
#pragma unroll
    for (int off = 32; off; off >>= 1) val += __shfl_down(val, off);
    __shared__ float sm[5];
    if ((t & 63) == 0) sm[t >> 6] = val;
    __syncthreads();
    if (t == 0) {
        float tot = sm[0] + sm[1] + sm[2] + sm[3] + sm[4];
        out[0] = tot / ((float)NPIX * (float)C_);
    }
}

extern "C" void kernel_launch(void* const* d_in, const int* in_sizes, int n_in,
                              void* d_out, int out_size, void* d_ws, size_t ws_size,
                              hipStream_t stream) {
    const float* logits = (const float*)d_in[0];
    const int*   labels = (const int*)d_in[1];
    float* out = (float*)d_out;
    float* ws  = (float*)d_ws;

    hipMemsetAsync(ws, 0, (size_t)KCOP * CB * sizeof(float), stream);
    ece_hist<<<GBLK, TPB, 0, stream>>>(logits, labels, ws);
    ece_final<<<1, 320, 0, stream>>>(ws, out);
}

// Round 12
// 65.742 us; speedup vs baseline: 3.9701x; 3.9701x over previous
//
#include <hip/hip_runtime.h>

#define C_    19
#define NB    15
#define CB    (C_ * NB)          // 285 cells
#define HW    (512 * 1024)
#define NPIX  (4 * HW)           // 2097152
#define REPS  4                  // LDS replicas for bin>=2 atomics
#define TPB   256
#define GBLK  2048               // 8 blocks/CU; VGPR (not LDS) decides residency
#define KCOP  8                  // global histogram copies

// Occupancy experiment: R2's proven scalar-load structure + merged-cell
// cumulative rows (d0: tt<=1, d1: tt<=2; 38 regs) + bin>=2 LDS atomics
// (~1.5/px, REPS=4) at 8 blocks/CU. No per-pixel global atomics (R11 lesson).
// cell += conf - (c==label); final = sum |cell| / (N*C).
__global__ __launch_bounds__(TPB, 4)
void ece_hist(const float* __restrict__ logits,
              const int*   __restrict__ labels,
              float*       __restrict__ ws) {
    __shared__ float hist[REPS * CB];    // 4560 B

    const int tid = threadIdx.x;
    for (int i = tid; i < REPS * CB; i += TPB) hist[i] = 0.f;
    __syncthreads();

    float* myh = hist + (tid & (REPS - 1)) * CB;

    float d0[C_], d1[C_];                // cumulative rows: tt<=1 (bin0), tt<=2 (bins<=1)
#pragma unroll
    for (int c = 0; c < C_; ++c) { d0[c] = 0.f; d1[c] = 0.f; }

    for (int n = blockIdx.x * TPB + tid; n < NPIX; n += GBLK * TPB) {   // 4 iters
        const int b  = n >> 19;                    // HW = 2^19
        const int hw = n & (HW - 1);
        const float* base = logits + ((size_t)b * C_) * HW + hw;

        float x[C_];
#pragma unroll
        for (int c = 0; c < C_; ++c) x[c] = base[(size_t)c * HW];  // 19 streams in flight
        const int l = labels[n];

        float s = 0.f;
#pragma unroll
        for (int c = 0; c < C_; ++c) { x[c] = __expf(x[c]); s += x[c]; }
        const float inv = 1.f / s;

#pragma unroll
        for (int c = 0; c < C_; ++c) {
            const float conf = x[c] * inv;
            const float tt   = conf * 15.f;        // ref bin = ceil(tt)-1 clamped
            const float val  = conf - ((c == l) ? 1.f : 0.f);
            d0[c] += (tt <= 1.f) ? val : 0.f;
            d1[c] += (tt <= 2.f) ? val : 0.f;
            if (tt > 2.f) {                        // ~1.5/px -> LDS replica hist
                int bin = (int)ceilf(tt) - 1;
                bin = bin > NB - 1 ? NB - 1 : bin;
                atomicAdd(&myh[c * NB + bin], val);
            }
        }
    }

    // Flush: 3-step xor-shuffle (8-lane groups) -> leader ds-atomics.
    // Telescoping: bin0 = d0, bin1 = d1 - d0.
#pragma unroll
    for (int c = 0; c < C_; ++c) {
        float r0 = d0[c], r1 = d1[c];
        r0 += __shfl_xor(r0, 1); r1 += __shfl_xor(r1, 1);
        r0 += __shfl_xor(r0, 2); r1 += __shfl_xor(r1, 2);
        r0 += __shfl_xor(r0, 4); r1 += __shfl_xor(r1, 4);
        if ((tid & 7) == 0) {
            const int r = (tid >> 3) & (REPS - 1);
            atomicAdd(&hist[r * CB + c * NB + 0], r0);
            atomicAdd(&hist[r * CB + c * NB + 1], r1 - r0);
        }
    }
    __syncthreads();

    // Fold replicas -> one global atomic per cell into one of KCOP copies.
    float* wsb = ws + (size_t)(blockIdx.x & (KCOP - 1)) * CB;
    for (int i = tid; i < CB; i += TPB) {
        float s = 0.f;
#pragma unroll
        for (int r = 0; r < REPS; ++r) s += hist[r * CB + i];
        atomicAdd(&wsb[i], s);
    }
}

// Fold KCOP copies: sce = sum_cells |cell| / (N * C)
__global__ void ece_final(const float* __restrict__ ws, float* __restrict__ out) {
    const int t = threadIdx.x;  // 320 threads = 5 waves
    float val = 0.f;
    if (t < CB) {
        float s = 0.f;
#pragma unroll
        for (int k = 0; k < KCOP; ++k) s += ws[k * CB + t];
        val = fabsf(s);
    }
#pragma unroll
    for (int off = 32; off; off >>= 1) val += __shfl_down(val, off);
    __shared__ float sm[5];
    if ((t & 63) == 0) sm[t >> 6] = val;
    __syncthreads();
    if (t == 0) {
        float tot = sm[0] + sm[1] + sm[2] + sm[3] + sm[4];
        out[0] = tot / ((float)NPIX * (float)C_);
    }
}

extern "C" void kernel_launch(void* const* d_in, const int* in_sizes, int n_in,
                              void* d_out, int out_size, void* d_ws, size_t ws_size,
                              hipStream_t stream) {
    const float* logits = (const float*)d_in[0];
    const int*   labels = (const int*)d_in[1];
    float* out = (float*)d_out;
    float* ws  = (float*)d_ws;

    hipMemsetAsync(ws, 0, (size_t)KCOP * CB * sizeof(float), stream);
    ece_hist<<<GBLK, TPB, 0, stream>>>(logits, labels, ws);
    ece_final<<<1, 320, 0, stream>>>(ws, out);
}